// Round 1
// baseline (661.214 us; speedup 1.0000x reference)
//
#include <hip/hip_runtime.h>

#define HIDDEN 15
#define NLAYERS 5          // DEPTH-1 hidden 1x1 conv layers
#define XDIM 8192
#define XOUT 8191
#define P 4                // positions per thread

__device__ __forceinline__ void layer15(const float (&src)[P][HIDDEN],
                                        float (&dst)[P][HIDDEN],
                                        const float* __restrict__ W,
                                        const float* __restrict__ bb) {
#pragma unroll
    for (int o = 0; o < HIDDEN; ++o) {
        float acc0 = bb[o];
        float acc1 = bb[o];
        float acc2 = bb[o];
        float acc3 = bb[o];
#pragma unroll
        for (int i = 0; i < HIDDEN; ++i) {
            const float w = W[o * HIDDEN + i];   // uniform -> s_load, SGPR operand
            acc0 = fmaf(w, src[0][i], acc0);
            acc1 = fmaf(w, src[1][i], acc1);
            acc2 = fmaf(w, src[2][i], acc2);
            acc3 = fmaf(w, src[3][i], acc3);
        }
        dst[0][o] = fmaxf(acc0, 0.0f);
        dst[1][o] = fmaxf(acc1, 0.0f);
        dst[2][o] = fmaxf(acc2, 0.0f);
        dst[3][o] = fmaxf(acc3, 0.0f);
    }
}

__global__ __launch_bounds__(256, 2) void cnn_stencil_kernel(
    const float* __restrict__ rho,
    const float* __restrict__ w0,
    const float* __restrict__ b0,
    const float* __restrict__ Wh,
    const float* __restrict__ bh,
    const float* __restrict__ Wl,
    const float* __restrict__ bl,
    float* __restrict__ out) {
    const int b = blockIdx.x >> 3;          // 8 blocks per row
    const int chunk = blockIdx.x & 7;
    const int xbase = chunk * 1024 + threadIdx.x;   // + p*256, p in [0,4)
    const float* rrow = rho + (size_t)b * XDIM;
    float* orow = out + (size_t)b * XOUT;

    float A[P][HIDDEN];
    float B[P][HIDDEN];

    // ---- first conv: kernel_size=2, in=1, out=HIDDEN ----
#pragma unroll
    for (int p = 0; p < P; ++p) {
        const int x = xbase + p * 256;      // <= 8191 always
        int xn = x + 1;
        if (xn > XDIM - 1) xn = XDIM - 1;   // clamp; that lane's output is masked
        const float r0 = rrow[x];
        const float r1 = rrow[xn];
#pragma unroll
        for (int c = 0; c < HIDDEN; ++c) {
            const float v = fmaf(r0, w0[2 * c], fmaf(r1, w0[2 * c + 1], b0[c]));
            A[p][c] = fmaxf(v, 0.0f);
        }
    }

    // ---- 5 hidden 15x15 pointwise layers (ping-pong, static indexing) ----
    layer15(A, B, Wh + 0 * HIDDEN * HIDDEN, bh + 0 * HIDDEN);
    layer15(B, A, Wh + 1 * HIDDEN * HIDDEN, bh + 1 * HIDDEN);
    layer15(A, B, Wh + 2 * HIDDEN * HIDDEN, bh + 2 * HIDDEN);
    layer15(B, A, Wh + 3 * HIDDEN * HIDDEN, bh + 3 * HIDDEN);
    layer15(A, B, Wh + 4 * HIDDEN * HIDDEN, bh + 4 * HIDDEN);
    // result in B

    // ---- final 1x1 conv to scalar + clip ----
    const float bias = bl[0];
#pragma unroll
    for (int p = 0; p < P; ++p) {
        float acc = bias;
#pragma unroll
        for (int i = 0; i < HIDDEN; ++i) {
            acc = fmaf(Wl[i], B[p][i], acc);
        }
        acc = fminf(fmaxf(acc, 0.0f), 1.0f);
        const int x = xbase + p * 256;
        if (x < XOUT) orow[x] = acc;
    }
}

extern "C" void kernel_launch(void* const* d_in, const int* in_sizes, int n_in,
                              void* d_out, int out_size, void* d_ws, size_t ws_size,
                              hipStream_t stream) {
    const float* rho = (const float*)d_in[0];
    const float* w0  = (const float*)d_in[1];
    const float* b0  = (const float*)d_in[2];
    const float* Wh  = (const float*)d_in[3];
    const float* bh  = (const float*)d_in[4];
    const float* Wl  = (const float*)d_in[5];
    const float* bl  = (const float*)d_in[6];
    float* out = (float*)d_out;

    const int nrows = 1024;
    dim3 grid(nrows * 8);   // 8 blocks of 256 threads cover 8192 x-slots per row
    dim3 block(256);
    cnn_stencil_kernel<<<grid, block, 0, stream>>>(rho, w0, b0, Wh, bh, Wl, bl, out);
}

// Round 2
// 564.395 us; speedup vs baseline: 1.1715x; 1.1715x over previous
//
#include <hip/hip_runtime.h>

#define HIDDEN 15
#define XDIM 8192
#define XOUT 8191

// Struct of NAMED scalars: no indexing possible -> guaranteed register allocation.
struct H {
    float v0, v1, v2, v3, v4, v5, v6, v7, v8, v9, v10, v11, v12, v13, v14;
};

#define REP15(F) F(0) F(1) F(2) F(3) F(4) F(5) F(6) F(7) F(8) F(9) F(10) F(11) F(12) F(13) F(14)

// 15-term dot product as a nested fmaf chain (weights have compile-time
// offsets from a uniform pointer -> s_load -> SGPR operand of v_fmac_f32).
#define DOT15(Wp_, S, B0)                                       \
    fmaf((Wp_)[0],  (S).v0,                                     \
    fmaf((Wp_)[1],  (S).v1,                                     \
    fmaf((Wp_)[2],  (S).v2,                                     \
    fmaf((Wp_)[3],  (S).v3,                                     \
    fmaf((Wp_)[4],  (S).v4,                                     \
    fmaf((Wp_)[5],  (S).v5,                                     \
    fmaf((Wp_)[6],  (S).v6,                                     \
    fmaf((Wp_)[7],  (S).v7,                                     \
    fmaf((Wp_)[8],  (S).v8,                                     \
    fmaf((Wp_)[9],  (S).v9,                                     \
    fmaf((Wp_)[10], (S).v10,                                    \
    fmaf((Wp_)[11], (S).v11,                                    \
    fmaf((Wp_)[12], (S).v12,                                    \
    fmaf((Wp_)[13], (S).v13,                                    \
    fmaf((Wp_)[14], (S).v14, (B0))))))))))))))))

__device__ __forceinline__ void fconv(H& dst, float r0, float r1,
                                      const float* __restrict__ w0,
                                      const float* __restrict__ b0) {
#define FC_O(o) dst.v##o = fmaxf(fmaf(r0, w0[2*(o)], fmaf(r1, w0[2*(o)+1], b0[(o)])), 0.0f);
    REP15(FC_O)
#undef FC_O
}

__device__ __forceinline__ void layer(const H& src, H& dst,
                                      const float* __restrict__ Wp,
                                      const float* __restrict__ Bp) {
#define LAYER_O(o) dst.v##o = fmaxf(DOT15(&Wp[(o)*HIDDEN], src, Bp[(o)]), 0.0f);
    REP15(LAYER_O)
#undef LAYER_O
}

__device__ __forceinline__ float eval_net(float r0, float r1,
                                          const float* __restrict__ w0,
                                          const float* __restrict__ b0,
                                          const float* __restrict__ Wh,
                                          const float* __restrict__ bh,
                                          const float* __restrict__ Wl,
                                          float bl0) {
    H a, t;
    fconv(a, r0, r1, w0, b0);
    layer(a, t, Wh + 0 * HIDDEN * HIDDEN, bh + 0 * HIDDEN);
    layer(t, a, Wh + 1 * HIDDEN * HIDDEN, bh + 1 * HIDDEN);
    layer(a, t, Wh + 2 * HIDDEN * HIDDEN, bh + 2 * HIDDEN);
    layer(t, a, Wh + 3 * HIDDEN * HIDDEN, bh + 3 * HIDDEN);
    layer(a, t, Wh + 4 * HIDDEN * HIDDEN, bh + 4 * HIDDEN);
    const float o = DOT15(Wl, t, bl0);
    return fminf(fmaxf(o, 0.0f), 1.0f);
}

__global__ __launch_bounds__(256, 2) void cnn_stencil_kernel(
    const float* __restrict__ rho,
    const float* __restrict__ w0,
    const float* __restrict__ b0,
    const float* __restrict__ Wh,
    const float* __restrict__ bh,
    const float* __restrict__ Wl,
    const float* __restrict__ bl,
    float* __restrict__ out) {
    const int b = blockIdx.x >> 4;           // 16 blocks per row
    const int chunk = blockIdx.x & 15;
    const int x0 = chunk * 512 + threadIdx.x;  // [0, 7935]
    const int x1 = x0 + 256;                   // [256, 8191]
    const float* rrow = rho + (size_t)b * XDIM;
    float* orow = out + (size_t)b * XOUT;

    const float ra0 = rrow[x0];
    const float ra1 = rrow[x0 + 1];            // x0+1 <= 7936, always in bounds
    const float rb0 = rrow[x1];
    const int x1n = (x1 + 1 <= XDIM - 1) ? (x1 + 1) : (XDIM - 1);  // clamp last
    const float rb1 = rrow[x1n];

    const float bl0 = bl[0];
    const float y0 = eval_net(ra0, ra1, w0, b0, Wh, bh, Wl, bl0);
    const float y1 = eval_net(rb0, rb1, w0, b0, Wh, bh, Wl, bl0);

    orow[x0] = y0;                 // x0 <= 7935 < 8191, always valid
    if (x1 < XOUT) orow[x1] = y1;  // mask the single x==8191 slot
}

extern "C" void kernel_launch(void* const* d_in, const int* in_sizes, int n_in,
                              void* d_out, int out_size, void* d_ws, size_t ws_size,
                              hipStream_t stream) {
    const float* rho = (const float*)d_in[0];
    const float* w0  = (const float*)d_in[1];
    const float* b0  = (const float*)d_in[2];
    const float* Wh  = (const float*)d_in[3];
    const float* bh  = (const float*)d_in[4];
    const float* Wl  = (const float*)d_in[5];
    const float* bl  = (const float*)d_in[6];
    float* out = (float*)d_out;

    const int nrows = 1024;
    dim3 grid(nrows * 16);   // 16 blocks x 256 threads x 2 positions = 8192 x-slots/row
    dim3 block(256);
    cnn_stencil_kernel<<<grid, block, 0, stream>>>(rho, w0, b0, Wh, bh, Wl, bl, out);
}